// Round 2
// baseline (480.758 us; speedup 1.0000x reference)
//
#include <hip/hip_runtime.h>
#include <math.h>

typedef _Float16 half8 __attribute__((ext_vector_type(8)));
typedef float f32x4 __attribute__((ext_vector_type(4)));
typedef float fvec4 __attribute__((ext_vector_type(4)));

#define NN   512
#define SS   64
#define HMID 128
#define MM   64

// ---------------------------------------------------------------------------
// prep0: Hi = b[i]*w_bi, Hj = b[j]*w_bj + mb1   (h == 0 at step 0)
// ---------------------------------------------------------------------------
__global__ void prep0_kernel(const float* __restrict__ b,
                             const float* __restrict__ mW1,
                             const float* __restrict__ mb1,
                             float* __restrict__ Hi, float* __restrict__ Hj) {
    int gid = blockIdx.x * 256 + threadIdx.x;      // 0..65535
    int node = gid >> 7, dm = gid & 127;
    float bn = b[node];
    Hi[gid] = bn * mW1[129 * HMID + dm];
    Hj[gid] = bn * mW1[130 * HMID + dm] + mb1[dm];
}

// ---------------------------------------------------------------------------
// transpose W_ih / W_hh (192x64 -> 64x192) for coalesced GRU reads
// ---------------------------------------------------------------------------
__global__ void transpose_w_kernel(const float* __restrict__ W_ih,
                                   const float* __restrict__ W_hh,
                                   float* __restrict__ WT_ih,
                                   float* __restrict__ WT_hh) {
    int idx = blockIdx.x * 256 + threadIdx.x;
    if (idx < 192 * 64) {
        int g = idx / 64, k = idx % 64;
        WT_ih[k * 192 + g] = W_ih[idx];
        WT_hh[k * 192 + g] = W_hh[idx];
    }
}

// ---------------------------------------------------------------------------
// main: (4 x 16) pair tiles, double-f16 (hi+lo) MFMA, 3-term products.
// Grid: 1024 blocks; block b: j-tile = b&31 (fixed), i-tiles (b>>5)*4 + tt.
// ---------------------------------------------------------------------------
__global__ __launch_bounds__(256) void main_step_kernel(
    const float* __restrict__ Hi, const float* __restrict__ Hj,
    const float* __restrict__ J, const float* __restrict__ wJ_g,
    const float* __restrict__ mW2, const float* __restrict__ mb2,
    const float* __restrict__ mW3, float* __restrict__ msg) {

    __shared__ __align__(16) _Float16 H1h[64 * 128];   // 16 KB each
    __shared__ __align__(16) _Float16 H1l[64 * 128];
    __shared__ __align__(16) _Float16 H2h[64 * 128];
    __shared__ __align__(16) _Float16 H2l[64 * 128];
    __shared__ __align__(16) float HiT[4 * 128];
    __shared__ __align__(16) float HjT[16 * 136];
    __shared__ float Jt[64];
    __shared__ float wJs[128];

    const int t   = threadIdx.x;
    const int w   = t >> 6;      // wave 0..3
    const int l   = t & 63;
    const int l16 = l & 15;
    const int lg  = l >> 4;      // 0..3

    const int j0 = (blockIdx.x & 31) * 16;
    const int ib = blockIdx.x >> 5;          // 0..31

    // ---- stage HjT (fixed for this block) + wJs ----
    if (t < 128) wJs[t] = wJ_g[t];
    #pragma unroll
    for (int rep = 0; rep < 2; ++rep) {
        int idx = t + rep * 256;
        int lj = idx >> 5, d2 = (idx & 31) * 4;
        *(fvec4*)&HjT[lj * 136 + d2] =
            *(const fvec4*)&Hj[(j0 + lj) * HMID + d2];
    }

    // ---- weight fragments (hi+lo f16) in registers ----
    half8 w2h[2][4], w2l[2][4], w3h[4], w3l[4];
    float mb2v[2];
    #pragma unroll
    for (int nb = 0; nb < 2; ++nb) {
        int col = w * 32 + nb * 16 + l16;
        mb2v[nb] = mb2[col];
        #pragma unroll
        for (int kb = 0; kb < 4; ++kb)
            #pragma unroll
            for (int i = 0; i < 8; ++i) {
                int k = kb * 32 + lg * 8 + i;
                float wv = mW2[k * HMID + col];
                _Float16 hh = (_Float16)wv;
                w2h[nb][kb][i] = hh;
                w2l[nb][kb][i] = (_Float16)(wv - (float)hh);
            }
    }
    {
        int col = w * 16 + l16;
        #pragma unroll
        for (int kb = 0; kb < 4; ++kb)
            #pragma unroll
            for (int i = 0; i < 8; ++i) {
                int k = kb * 32 + lg * 8 + i;
                float wv = mW3[k * MM + col];
                _Float16 hh = (_Float16)wv;
                w3h[kb][i] = hh;
                w3l[kb][i] = (_Float16)(wv - (float)hh);
            }
    }

    float psum[4] = {0.f, 0.f, 0.f, 0.f};

    for (int tt = 0; tt < 4; ++tt) {
        int i0 = (ib * 4 + tt) * 4;

        // ---- stage HiT (4x128) and Jt (4x16) ----
        if (t < 128) {
            int li = t >> 5, doff = (t & 31) * 4;
            *(fvec4*)&HiT[li * 128 + doff] =
                *(const fvec4*)&Hi[(i0 + li) * HMID + doff];
        } else if (t < 192) {
            int q = t - 128;
            Jt[q] = J[(i0 + (q >> 4)) * NN + j0 + (q & 15)];
        }
        __syncthreads();

        // ---- pre-phase: H1 = relu(Hi + Hj + J*wJ), split -> f16 hi/lo ----
        {
            int lj = t >> 4;    // 0..15
            int c  = t & 15;    // chunk of 8
            #pragma unroll
            for (int it = 0; it < 4; ++it) {
                int p = it * 16 + lj;
                float Jw = Jt[it * 16 + lj];
                fvec4 hi0 = *(const fvec4*)&HiT[it * 128 + c * 8];
                fvec4 hi1 = *(const fvec4*)&HiT[it * 128 + c * 8 + 4];
                fvec4 hj0 = *(const fvec4*)&HjT[lj * 136 + c * 8];
                fvec4 hj1 = *(const fvec4*)&HjT[lj * 136 + c * 8 + 4];
                fvec4 wj0 = *(const fvec4*)&wJs[c * 8];
                fvec4 wj1 = *(const fvec4*)&wJs[c * 8 + 4];
                half8 hvh, hvl;
                #pragma unroll
                for (int u = 0; u < 4; ++u) {
                    float v0 = hi0[u] + hj0[u] + Jw * wj0[u];
                    float v1 = hi1[u] + hj1[u] + Jw * wj1[u];
                    v0 = v0 > 0.f ? v0 : 0.f;
                    v1 = v1 > 0.f ? v1 : 0.f;
                    _Float16 h0 = (_Float16)v0, h1 = (_Float16)v1;
                    hvh[u]     = h0;
                    hvh[u + 4] = h1;
                    hvl[u]     = (_Float16)(v0 - (float)h0);
                    hvl[u + 4] = (_Float16)(v1 - (float)h1);
                }
                int addr = p * 128 + ((c ^ (p & 15)) << 3);
                *(half8*)&H1h[addr] = hvh;
                *(half8*)&H1l[addr] = hvl;
            }
        }
        __syncthreads();

        // ---- GEMM1: H2 = relu(H1 @ mW2 + mb2), 3-term double-f16 ----
        {
            f32x4 acc[4][2];
            #pragma unroll
            for (int mb = 0; mb < 4; ++mb)
                #pragma unroll
                for (int nb = 0; nb < 2; ++nb)
                    acc[mb][nb] = (f32x4){0.f, 0.f, 0.f, 0.f};
            #pragma unroll
            for (int kb = 0; kb < 4; ++kb) {
                #pragma unroll
                for (int mb = 0; mb < 4; ++mb) {
                    int row = mb * 16 + l16;
                    int base = row * 128 + (((kb * 4 + lg) ^ l16) << 3);
                    half8 ah = *(const half8*)&H1h[base];
                    half8 al = *(const half8*)&H1l[base];
                    #pragma unroll
                    for (int nb = 0; nb < 2; ++nb) {
                        acc[mb][nb] = __builtin_amdgcn_mfma_f32_16x16x32_f16(
                            ah, w2h[nb][kb], acc[mb][nb], 0, 0, 0);
                        acc[mb][nb] = __builtin_amdgcn_mfma_f32_16x16x32_f16(
                            al, w2h[nb][kb], acc[mb][nb], 0, 0, 0);
                        acc[mb][nb] = __builtin_amdgcn_mfma_f32_16x16x32_f16(
                            ah, w2l[nb][kb], acc[mb][nb], 0, 0, 0);
                    }
                }
            }
            // epilogue: +bias, relu, split -> H2 hi/lo (swizzled)
            #pragma unroll
            for (int mb = 0; mb < 4; ++mb)
                #pragma unroll
                for (int nb = 0; nb < 2; ++nb)
                    #pragma unroll
                    for (int q = 0; q < 4; ++q) {
                        int row = mb * 16 + lg * 4 + q;
                        int col = w * 32 + nb * 16 + l16;
                        float v = acc[mb][nb][q] + mb2v[nb];
                        v = v > 0.f ? v : 0.f;
                        _Float16 vh = (_Float16)v;
                        int addr = row * 128 + (((col >> 3) ^ (row & 15)) << 3)
                                   + (col & 7);
                        H2h[addr] = vh;
                        H2l[addr] = (_Float16)(v - (float)vh);
                    }
        }
        __syncthreads();

        // ---- GEMM2 (3-term) + i-reduction into psum ----
        {
            f32x4 acc2[4];
            #pragma unroll
            for (int mb = 0; mb < 4; ++mb) acc2[mb] = (f32x4){0.f, 0.f, 0.f, 0.f};
            #pragma unroll
            for (int kb = 0; kb < 4; ++kb) {
                #pragma unroll
                for (int mb = 0; mb < 4; ++mb) {
                    int row = mb * 16 + l16;
                    int base = row * 128 + (((kb * 4 + lg) ^ l16) << 3);
                    half8 ah = *(const half8*)&H2h[base];
                    half8 al = *(const half8*)&H2l[base];
                    acc2[mb] = __builtin_amdgcn_mfma_f32_16x16x32_f16(
                        ah, w3h[kb], acc2[mb], 0, 0, 0);
                    acc2[mb] = __builtin_amdgcn_mfma_f32_16x16x32_f16(
                        al, w3h[kb], acc2[mb], 0, 0, 0);
                    acc2[mb] = __builtin_amdgcn_mfma_f32_16x16x32_f16(
                        ah, w3l[kb], acc2[mb], 0, 0, 0);
                }
            }
            #pragma unroll
            for (int mb = 0; mb < 4; ++mb)
                #pragma unroll
                for (int q = 0; q < 4; ++q) psum[q] += acc2[mb][q];
        }
        __syncthreads();
    }

    // ---- one atomic per (j, col) per block ----
    {
        int col = w * 16 + l16;
        #pragma unroll
        for (int q = 0; q < 4; ++q)
            atomicAdd(&msg[(j0 + lg * 4 + q) * MM + col], psum[q]);
    }
}

// ---------------------------------------------------------------------------
// GRU update + next-step Hi/Hj.  1 wave per node, 512 blocks x 64 threads.
// ---------------------------------------------------------------------------
__global__ __launch_bounds__(64) void gru_kernel(
    const float* __restrict__ msg, const float* __restrict__ mb3,
    const float* __restrict__ WT_ih, const float* __restrict__ b_ih,
    const float* __restrict__ WT_hh, const float* __restrict__ b_hh,
    float* __restrict__ h, const float* __restrict__ bvec,
    const float* __restrict__ mW1, const float* __restrict__ mb1,
    float* __restrict__ Hi, float* __restrict__ Hj, int lastStep) {

    __shared__ float xb[64], hb[64], hnb[64];
    int d = threadIdx.x;
    int node = blockIdx.x;

    float x = msg[node * MM + d] + 512.0f * mb3[d];
    float hv = h[node * SS + d];
    xb[d] = x;
    hb[d] = hv;
    __syncthreads();

    float gxr = b_ih[d], gxz = b_ih[64 + d], gxn = b_ih[128 + d];
    float ghr = b_hh[d], ghz = b_hh[64 + d], ghn = b_hh[128 + d];
    for (int k = 0; k < 64; ++k) {
        float xk = xb[k], hk = hb[k];
        const float* wi = &WT_ih[k * 192];
        const float* wh = &WT_hh[k * 192];
        gxr += wi[d] * xk;
        gxz += wi[64 + d] * xk;
        gxn += wi[128 + d] * xk;
        ghr += wh[d] * hk;
        ghz += wh[64 + d] * hk;
        ghn += wh[128 + d] * hk;
    }
    float r = 1.f / (1.f + expf(-(gxr + ghr)));
    float z = 1.f / (1.f + expf(-(gxz + ghz)));
    float nc = tanhf(gxn + r * ghn);
    float hnew = (1.f - z) * nc + z * hv;
    h[node * SS + d] = hnew;
    hnb[d] = hnew;
    __syncthreads();

    if (!lastStep) {
        float bn = bvec[node];
        for (int dd = 0; dd < 2; ++dd) {
            int dm = d + dd * 64;
            float ai = bn * mW1[129 * HMID + dm];
            float aj = bn * mW1[130 * HMID + dm] + mb1[dm];
            for (int k = 0; k < 64; ++k) {
                float hk = hnb[k];
                ai += hk * mW1[k * HMID + dm];
                aj += hk * mW1[(64 + k) * HMID + dm];
            }
            Hi[node * HMID + dm] = ai;
            Hj[node * HMID + dm] = aj;
        }
    }
}

// ---------------------------------------------------------------------------
// readout: relu(h@rW1+rb1) -> relu(@rW2+rb2) -> @rW3+rb3 -> softmax(2)
// ---------------------------------------------------------------------------
__global__ __launch_bounds__(64) void readout_kernel(
    const float* __restrict__ h, const float* __restrict__ rW1,
    const float* __restrict__ rb1, const float* __restrict__ rW2,
    const float* __restrict__ rb2, const float* __restrict__ rW3,
    const float* __restrict__ rb3, float* __restrict__ out) {

    __shared__ float hbuf[64], o1[128], o2[128];
    int d = threadIdx.x;
    int node = blockIdx.x;

    hbuf[d] = h[node * SS + d];
    __syncthreads();
    for (int dd = 0; dd < 2; ++dd) {
        int dm = d + dd * 64;
        float a = rb1[dm];
        for (int k = 0; k < 64; ++k) a += hbuf[k] * rW1[k * 128 + dm];
        o1[dm] = a > 0.f ? a : 0.f;
    }
    __syncthreads();
    for (int dd = 0; dd < 2; ++dd) {
        int dm = d + dd * 64;
        float a = rb2[dm];
        for (int k = 0; k < 128; ++k) a += o1[k] * rW2[k * 128 + dm];
        o2[dm] = a > 0.f ? a : 0.f;
    }
    __syncthreads();
    float p0 = 0.f, p1 = 0.f;
    for (int dd = 0; dd < 2; ++dd) {
        int k = d + dd * 64;
        p0 += o2[k] * rW3[k * 2 + 0];
        p1 += o2[k] * rW3[k * 2 + 1];
    }
    for (int off = 32; off; off >>= 1) {
        p0 += __shfl_xor(p0, off);
        p1 += __shfl_xor(p1, off);
    }
    if (d == 0) {
        p0 += rb3[0];
        p1 += rb3[1];
        float m = fmaxf(p0, p1);
        float e0 = expf(p0 - m), e1 = expf(p1 - m);
        float s = e0 + e1;
        out[node * 2 + 0] = e0 / s;
        out[node * 2 + 1] = e1 / s;
    }
}

// ---------------------------------------------------------------------------
extern "C" void kernel_launch(void* const* d_in, const int* in_sizes, int n_in,
                              void* d_out, int out_size, void* d_ws,
                              size_t ws_size, hipStream_t stream) {
    const float* J    = (const float*)d_in[0];
    const float* b    = (const float*)d_in[1];
    const float* mW1  = (const float*)d_in[2];
    const float* mb1  = (const float*)d_in[3];
    const float* mW2  = (const float*)d_in[4];
    const float* mb2  = (const float*)d_in[5];
    const float* mW3  = (const float*)d_in[6];
    const float* mb3  = (const float*)d_in[7];
    const float* W_ih = (const float*)d_in[8];
    const float* b_ih = (const float*)d_in[9];
    const float* W_hh = (const float*)d_in[10];
    const float* b_hh = (const float*)d_in[11];
    const float* rW1  = (const float*)d_in[12];
    const float* rb1  = (const float*)d_in[13];
    const float* rW2  = (const float*)d_in[14];
    const float* rb2  = (const float*)d_in[15];
    const float* rW3  = (const float*)d_in[16];
    const float* rb3  = (const float*)d_in[17];
    float* out = (float*)d_out;

    float* ws    = (float*)d_ws;
    float* hbuf  = ws;                    // 512*64
    float* msg   = ws + 32768;            // 512*64
    float* Hi    = ws + 65536;            // 512*128
    float* Hj    = ws + 131072;           // 512*128
    float* WT_ih = ws + 196608;           // 64*192
    float* WT_hh = ws + 208896;           // 64*192

    hipMemsetAsync(hbuf, 0, NN * SS * sizeof(float), stream);
    prep0_kernel<<<256, 256, 0, stream>>>(b, mW1, mb1, Hi, Hj);
    transpose_w_kernel<<<48, 256, 0, stream>>>(W_ih, W_hh, WT_ih, WT_hh);

    for (int s = 0; s < 5; ++s) {
        hipMemsetAsync(msg, 0, NN * MM * sizeof(float), stream);
        main_step_kernel<<<1024, 256, 0, stream>>>(Hi, Hj, J, mW1 + 128 * HMID,
                                                   mW2, mb2, mW3, msg);
        gru_kernel<<<512, 64, 0, stream>>>(msg, mb3, WT_ih, b_ih, WT_hh, b_hh,
                                           hbuf, b, mW1, mb1, Hi, Hj, s == 4);
    }
    readout_kernel<<<512, 64, 0, stream>>>(hbuf, rW1, rb1, rW2, rb2, rW3, rb3,
                                           out);
}

// Round 3
// 361.479 us; speedup vs baseline: 1.3300x; 1.3300x over previous
//
#include <hip/hip_runtime.h>
#include <math.h>
#include <stdint.h>

typedef _Float16 half8 __attribute__((ext_vector_type(8)));
typedef float f32x4 __attribute__((ext_vector_type(4)));
typedef float fvec4 __attribute__((ext_vector_type(4)));
typedef uint32_t u32x4 __attribute__((ext_vector_type(4)));

#define NN   512
#define SS   64
#define HMID 128
#define MM   64

// ---------------------------------------------------------------------------
// prep0: Hi = b[i]*w_bi, Hj = b[j]*w_bj + mb1   (h == 0 at step 0)
// ---------------------------------------------------------------------------
__global__ void prep0_kernel(const float* __restrict__ b,
                             const float* __restrict__ mW1,
                             const float* __restrict__ mb1,
                             float* __restrict__ Hi, float* __restrict__ Hj) {
    int gid = blockIdx.x * 256 + threadIdx.x;      // 0..65535
    int node = gid >> 7, dm = gid & 127;
    float bn = b[node];
    Hi[gid] = bn * mW1[129 * HMID + dm];
    Hj[gid] = bn * mW1[130 * HMID + dm] + mb1[dm];
}

// ---------------------------------------------------------------------------
// transpose W_ih / W_hh (192x64 -> 64x192) for coalesced GRU reads
// ---------------------------------------------------------------------------
__global__ void transpose_w_kernel(const float* __restrict__ W_ih,
                                   const float* __restrict__ W_hh,
                                   float* __restrict__ WT_ih,
                                   float* __restrict__ WT_hh) {
    int idx = blockIdx.x * 256 + threadIdx.x;
    if (idx < 192 * 64) {
        int g = idx / 64, k = idx % 64;
        WT_ih[k * 192 + g] = W_ih[idx];
        WT_hh[k * 192 + g] = W_hh[idx];
    }
}

// ---------------------------------------------------------------------------
// main: 64-pair tiles (4i x 16j), double-f16 3-term MFMA, 2-barrier pipeline:
//   P1: GEMM1(t) + epilogue->H2p + stage Hi/J(t+1)   | barrier
//   P2: GEMM2(t)  ||  pre(t+1)->H1                   | barrier
// Grid 512 = (32 j-blocks) x (16 i-groups), 8 tiles/block, 2 blocks/CU.
// ---------------------------------------------------------------------------
__global__ __launch_bounds__(256, 2) void main_step_kernel(
    const float* __restrict__ Hi, const float* __restrict__ Hj,
    const float* __restrict__ J, const float* __restrict__ wJ_g,
    const float* __restrict__ mW2, const float* __restrict__ mb2,
    const float* __restrict__ mW3, float* __restrict__ msg) {

    __shared__ __align__(16) _Float16 H1h[64 * 128];      // 16 KB
    __shared__ __align__(16) _Float16 H1l[64 * 128];      // 16 KB
    __shared__ __align__(16) uint32_t H2p[4 * 128 * 16];  // 32 KB (h,l packed)
    __shared__ __align__(16) float HiT[4 * 132];          // ~2.1 KB (padded)
    __shared__ float Jt[64];

    const int t   = threadIdx.x;
    const int w   = t >> 6;      // wave 0..3
    const int l   = t & 63;
    const int l16 = l & 15;
    const int lg  = l >> 4;      // 0..3

    const int j0 = (blockIdx.x & 31) * 16;
    const int ig = blockIdx.x >> 5;          // 0..15

    // ---- per-thread block-constant registers: Hj slice, wJ slice ----
    const int lj = t >> 4;       // 0..15  (pre-phase j index)
    const int c  = t & 15;       // 0..15  (pre-phase d-chunk)
    fvec4 hjv0 = *(const fvec4*)&Hj[(j0 + lj) * HMID + c * 8];
    fvec4 hjv1 = *(const fvec4*)&Hj[(j0 + lj) * HMID + c * 8 + 4];
    fvec4 wjv0 = *(const fvec4*)&wJ_g[c * 8];
    fvec4 wjv1 = *(const fvec4*)&wJ_g[c * 8 + 4];

    // ---- weight fragments (hi+lo f16) in registers ----
    half8 w2h[2][4], w2l[2][4], w3h[4], w3l[4];
    float mb2v[2];
    #pragma unroll
    for (int nb = 0; nb < 2; ++nb) {
        int col = w * 32 + nb * 16 + l16;
        mb2v[nb] = mb2[col];
        #pragma unroll
        for (int kb = 0; kb < 4; ++kb)
            #pragma unroll
            for (int i = 0; i < 8; ++i) {
                int k = kb * 32 + lg * 8 + i;
                float wv = mW2[k * HMID + col];
                _Float16 hh = (_Float16)wv;
                w2h[nb][kb][i] = hh;
                w2l[nb][kb][i] = (_Float16)(wv - (float)hh);
            }
    }
    {
        int col = w * 16 + l16;
        #pragma unroll
        for (int kb = 0; kb < 4; ++kb)
            #pragma unroll
            for (int i = 0; i < 8; ++i) {
                int k = kb * 32 + lg * 8 + i;
                float wv = mW3[k * MM + col];
                _Float16 hh = (_Float16)wv;
                w3h[kb][i] = hh;
                w3l[kb][i] = (_Float16)(wv - (float)hh);
            }
    }

    // ---- prologue: stage HiT/Jt for tile 0 ----
    if (t < 128) {
        int row = t >> 5, off = (t & 31) * 4;
        *(fvec4*)&HiT[row * 132 + off] =
            *(const fvec4*)&Hi[(ig * 32 + row) * HMID + off];
    }
    if (l < 16)
        Jt[w * 16 + l] = J[(ig * 32 + w) * NN + j0 + l];
    __syncthreads();

    // ---- pre(0): H1 = relu(Hi + Hj + J*wJ) -> f16 hi/lo (swizzled) ----
    auto do_pre = [&]() {
        #pragma unroll
        for (int it = 0; it < 4; ++it) {
            int p = it * 16 + lj;
            float Jw = Jt[p];
            fvec4 hi0 = *(const fvec4*)&HiT[it * 132 + c * 8];
            fvec4 hi1 = *(const fvec4*)&HiT[it * 132 + c * 8 + 4];
            half8 hvh, hvl;
            #pragma unroll
            for (int u = 0; u < 4; ++u) {
                float v0 = hi0[u] + hjv0[u] + Jw * wjv0[u];
                float v1 = hi1[u] + hjv1[u] + Jw * wjv1[u];
                v0 = v0 > 0.f ? v0 : 0.f;
                v1 = v1 > 0.f ? v1 : 0.f;
                _Float16 h0 = (_Float16)v0, h1 = (_Float16)v1;
                hvh[u]     = h0;
                hvh[u + 4] = h1;
                hvl[u]     = (_Float16)(v0 - (float)h0);
                hvl[u + 4] = (_Float16)(v1 - (float)h1);
            }
            int addr = p * 128 + ((c ^ lj) << 3);
            *(half8*)&H1h[addr] = hvh;
            *(half8*)&H1l[addr] = hvl;
        }
    };
    do_pre();
    __syncthreads();

    // persistent GEMM2 accumulators (summed over all i-tiles)
    f32x4 acc2[4];
    #pragma unroll
    for (int mb = 0; mb < 4; ++mb) acc2[mb] = (f32x4){0.f, 0.f, 0.f, 0.f};

    for (int tt = 0; tt < 8; ++tt) {
        // ================= P1: GEMM1(t) + epilogue + stage(t+1) ==========
        const int i0n = (ig * 8 + tt + 1) * 4;
        fvec4 hiStage;
        float jStage;
        const bool hasHi = (tt < 7) && (t < 128);
        const bool hasJ  = (tt < 7) && (l < 16);
        if (hasHi) {
            int row = t >> 5, off = (t & 31) * 4;
            hiStage = *(const fvec4*)&Hi[(i0n + row) * HMID + off];
        }
        if (hasJ) jStage = J[(i0n + w) * NN + j0 + l];

        {
            f32x4 acc[4][2];
            #pragma unroll
            for (int mb = 0; mb < 4; ++mb)
                #pragma unroll
                for (int nb = 0; nb < 2; ++nb)
                    acc[mb][nb] = (f32x4){0.f, 0.f, 0.f, 0.f};
            #pragma unroll
            for (int kb = 0; kb < 4; ++kb) {
                #pragma unroll
                for (int mb = 0; mb < 4; ++mb) {
                    int row = mb * 16 + l16;
                    int base = row * 128 + (((kb * 4 + lg) ^ l16) << 3);
                    half8 ah = *(const half8*)&H1h[base];
                    half8 al = *(const half8*)&H1l[base];
                    #pragma unroll
                    for (int nb = 0; nb < 2; ++nb) {
                        acc[mb][nb] = __builtin_amdgcn_mfma_f32_16x16x32_f16(
                            ah, w2h[nb][kb], acc[mb][nb], 0, 0, 0);
                        acc[mb][nb] = __builtin_amdgcn_mfma_f32_16x16x32_f16(
                            al, w2h[nb][kb], acc[mb][nb], 0, 0, 0);
                        acc[mb][nb] = __builtin_amdgcn_mfma_f32_16x16x32_f16(
                            ah, w2l[nb][kb], acc[mb][nb], 0, 0, 0);
                    }
                }
            }
            // epilogue: +bias, relu, split, pack (h,l)->u32, vector store
            #pragma unroll
            for (int mb = 0; mb < 4; ++mb)
                #pragma unroll
                for (int nbl = 0; nbl < 2; ++nbl) {
                    int col = w * 32 + nbl * 16 + l16;
                    u32x4 pk;
                    #pragma unroll
                    for (int q = 0; q < 4; ++q) {
                        float v = acc[mb][nbl][q] + mb2v[nbl];
                        v = v > 0.f ? v : 0.f;
                        _Float16 hh = (_Float16)v;
                        _Float16 ll = (_Float16)(v - (float)hh);
                        uint16_t uh = __builtin_bit_cast(uint16_t, hh);
                        uint16_t ul = __builtin_bit_cast(uint16_t, ll);
                        pk[q] = (uint32_t)uh | ((uint32_t)ul << 16);
                    }
                    int base = mb * 2048 + col * 16 + ((lg * 4) ^ (col & 12));
                    *(u32x4*)&H2p[base] = pk;
                }
        }
        // publish stage(t+1)
        if (hasHi) {
            int row = t >> 5, off = (t & 31) * 4;
            *(fvec4*)&HiT[row * 132 + off] = hiStage;
        }
        if (hasJ) Jt[w * 16 + l] = jStage;
        __syncthreads();

        // ================= P2: GEMM2(t)  ||  pre(t+1) ====================
        #pragma unroll
        for (int kb = 0; kb < 4; ++kb) {
            #pragma unroll
            for (int mb2 = 0; mb2 < 4; ++mb2) {
                uint32_t u[8];
                #pragma unroll
                for (int i2 = 0; i2 < 8; ++i2) {
                    int col = kb * 32 + lg * 8 + i2;
                    u[i2] = H2p[mb2 * 2048 + col * 16 + (l16 ^ (col & 12))];
                }
                union { uint32_t wd[4]; half8 v; } Ah, Al;
                #pragma unroll
                for (int k2 = 0; k2 < 4; ++k2) {
                    Ah.wd[k2] = __builtin_amdgcn_perm(u[2 * k2 + 1], u[2 * k2],
                                                      0x05040100u);
                    Al.wd[k2] = __builtin_amdgcn_perm(u[2 * k2 + 1], u[2 * k2],
                                                      0x07060302u);
                }
                acc2[mb2] = __builtin_amdgcn_mfma_f32_16x16x32_f16(
                    Ah.v, w3h[kb], acc2[mb2], 0, 0, 0);
                acc2[mb2] = __builtin_amdgcn_mfma_f32_16x16x32_f16(
                    Al.v, w3h[kb], acc2[mb2], 0, 0, 0);
                acc2[mb2] = __builtin_amdgcn_mfma_f32_16x16x32_f16(
                    Ah.v, w3l[kb], acc2[mb2], 0, 0, 0);
            }
        }
        if (tt < 7) do_pre();
        __syncthreads();
    }

    // ---- final: reduce over mb2 (i-blocks) and atomically add to msg ----
    {
        int colm = w * 16 + l16;
        #pragma unroll
        for (int q = 0; q < 4; ++q) {
            float s = acc2[0][q] + acc2[1][q] + acc2[2][q] + acc2[3][q];
            atomicAdd(&msg[(j0 + lg * 4 + q) * MM + colm], s);
        }
    }
}

// ---------------------------------------------------------------------------
// GRU update + next-step Hi/Hj.  1 wave per node, 512 blocks x 64 threads.
// ---------------------------------------------------------------------------
__global__ __launch_bounds__(64) void gru_kernel(
    const float* __restrict__ msg, const float* __restrict__ mb3,
    const float* __restrict__ WT_ih, const float* __restrict__ b_ih,
    const float* __restrict__ WT_hh, const float* __restrict__ b_hh,
    float* __restrict__ h, const float* __restrict__ bvec,
    const float* __restrict__ mW1, const float* __restrict__ mb1,
    float* __restrict__ Hi, float* __restrict__ Hj, int lastStep) {

    __shared__ float xb[64], hb[64], hnb[64];
    int d = threadIdx.x;
    int node = blockIdx.x;

    float x = msg[node * MM + d] + 512.0f * mb3[d];
    float hv = h[node * SS + d];
    xb[d] = x;
    hb[d] = hv;
    __syncthreads();

    float gxr = b_ih[d], gxz = b_ih[64 + d], gxn = b_ih[128 + d];
    float ghr = b_hh[d], ghz = b_hh[64 + d], ghn = b_hh[128 + d];
    for (int k = 0; k < 64; ++k) {
        float xk = xb[k], hk = hb[k];
        const float* wi = &WT_ih[k * 192];
        const float* wh = &WT_hh[k * 192];
        gxr += wi[d] * xk;
        gxz += wi[64 + d] * xk;
        gxn += wi[128 + d] * xk;
        ghr += wh[d] * hk;
        ghz += wh[64 + d] * hk;
        ghn += wh[128 + d] * hk;
    }
    float r = 1.f / (1.f + expf(-(gxr + ghr)));
    float z = 1.f / (1.f + expf(-(gxz + ghz)));
    float nc = tanhf(gxn + r * ghn);
    float hnew = (1.f - z) * nc + z * hv;
    h[node * SS + d] = hnew;
    hnb[d] = hnew;
    __syncthreads();

    if (!lastStep) {
        float bn = bvec[node];
        for (int dd = 0; dd < 2; ++dd) {
            int dm = d + dd * 64;
            float ai = bn * mW1[129 * HMID + dm];
            float aj = bn * mW1[130 * HMID + dm] + mb1[dm];
            for (int k = 0; k < 64; ++k) {
                float hk = hnb[k];
                ai += hk * mW1[k * HMID + dm];
                aj += hk * mW1[(64 + k) * HMID + dm];
            }
            Hi[node * HMID + dm] = ai;
            Hj[node * HMID + dm] = aj;
        }
    }
}

// ---------------------------------------------------------------------------
// readout: relu(h@rW1+rb1) -> relu(@rW2+rb2) -> @rW3+rb3 -> softmax(2)
// ---------------------------------------------------------------------------
__global__ __launch_bounds__(64) void readout_kernel(
    const float* __restrict__ h, const float* __restrict__ rW1,
    const float* __restrict__ rb1, const float* __restrict__ rW2,
    const float* __restrict__ rb2, const float* __restrict__ rW3,
    const float* __restrict__ rb3, float* __restrict__ out) {

    __shared__ float hbuf[64], o1[128], o2[128];
    int d = threadIdx.x;
    int node = blockIdx.x;

    hbuf[d] = h[node * SS + d];
    __syncthreads();
    for (int dd = 0; dd < 2; ++dd) {
        int dm = d + dd * 64;
        float a = rb1[dm];
        for (int k = 0; k < 64; ++k) a += hbuf[k] * rW1[k * 128 + dm];
        o1[dm] = a > 0.f ? a : 0.f;
    }
    __syncthreads();
    for (int dd = 0; dd < 2; ++dd) {
        int dm = d + dd * 64;
        float a = rb2[dm];
        for (int k = 0; k < 128; ++k) a += o1[k] * rW2[k * 128 + dm];
        o2[dm] = a > 0.f ? a : 0.f;
    }
    __syncthreads();
    float p0 = 0.f, p1 = 0.f;
    for (int dd = 0; dd < 2; ++dd) {
        int k = d + dd * 64;
        p0 += o2[k] * rW3[k * 2 + 0];
        p1 += o2[k] * rW3[k * 2 + 1];
    }
    for (int off = 32; off; off >>= 1) {
        p0 += __shfl_xor(p0, off);
        p1 += __shfl_xor(p1, off);
    }
    if (d == 0) {
        p0 += rb3[0];
        p1 += rb3[1];
        float m = fmaxf(p0, p1);
        float e0 = expf(p0 - m), e1 = expf(p1 - m);
        float s = e0 + e1;
        out[node * 2 + 0] = e0 / s;
        out[node * 2 + 1] = e1 / s;
    }
}

// ---------------------------------------------------------------------------
extern "C" void kernel_launch(void* const* d_in, const int* in_sizes, int n_in,
                              void* d_out, int out_size, void* d_ws,
                              size_t ws_size, hipStream_t stream) {
    const float* J    = (const float*)d_in[0];
    const float* b    = (const float*)d_in[1];
    const float* mW1  = (const float*)d_in[2];
    const float* mb1  = (const float*)d_in[3];
    const float* mW2  = (const float*)d_in[4];
    const float* mb2  = (const float*)d_in[5];
    const float* mW3  = (const float*)d_in[6];
    const float* mb3  = (const float*)d_in[7];
    const float* W_ih = (const float*)d_in[8];
    const float* b_ih = (const float*)d_in[9];
    const float* W_hh = (const float*)d_in[10];
    const float* b_hh = (const float*)d_in[11];
    const float* rW1  = (const float*)d_in[12];
    const float* rb1  = (const float*)d_in[13];
    const float* rW2  = (const float*)d_in[14];
    const float* rb2  = (const float*)d_in[15];
    const float* rW3  = (const float*)d_in[16];
    const float* rb3  = (const float*)d_in[17];
    float* out = (float*)d_out;

    float* ws    = (float*)d_ws;
    float* hbuf  = ws;                    // 512*64
    float* msg   = ws + 32768;            // 512*64
    float* Hi    = ws + 65536;            // 512*128
    float* Hj    = ws + 131072;           // 512*128
    float* WT_ih = ws + 196608;           // 64*192
    float* WT_hh = ws + 208896;           // 64*192

    hipMemsetAsync(hbuf, 0, NN * SS * sizeof(float), stream);
    prep0_kernel<<<256, 256, 0, stream>>>(b, mW1, mb1, Hi, Hj);
    transpose_w_kernel<<<48, 256, 0, stream>>>(W_ih, W_hh, WT_ih, WT_hh);

    for (int s = 0; s < 5; ++s) {
        hipMemsetAsync(msg, 0, NN * MM * sizeof(float), stream);
        main_step_kernel<<<512, 256, 0, stream>>>(Hi, Hj, J, mW1 + 128 * HMID,
                                                  mW2, mb2, mW3, msg);
        gru_kernel<<<512, 64, 0, stream>>>(msg, mb3, WT_ih, b_ih, WT_hh, b_hh,
                                           hbuf, b, mW1, mb1, Hi, Hj, s == 4);
    }
    readout_kernel<<<512, 64, 0, stream>>>(hbuf, rW1, rb1, rW2, rb2, rW3, rb3,
                                           out);
}

// Round 4
// 245.234 us; speedup vs baseline: 1.9604x; 1.4740x over previous
//
#include <hip/hip_runtime.h>
#include <math.h>
#include <stdint.h>

typedef _Float16 half8 __attribute__((ext_vector_type(8)));
typedef float f32x4 __attribute__((ext_vector_type(4)));
typedef float fvec4 __attribute__((ext_vector_type(4)));
typedef uint32_t u32x4 __attribute__((ext_vector_type(4)));

#define NN   512
#define SS   64
#define HMID 128
#define MM   64

// ---------------------------------------------------------------------------
// prep0: Hi = b[i]*w_bi, Hj = b[j]*w_bj + mb1   (h == 0 at step 0)
// ---------------------------------------------------------------------------
__global__ void prep0_kernel(const float* __restrict__ b,
                             const float* __restrict__ mW1,
                             const float* __restrict__ mb1,
                             float* __restrict__ Hi, float* __restrict__ Hj) {
    int gid = blockIdx.x * 256 + threadIdx.x;      // 0..65535
    int node = gid >> 7, dm = gid & 127;
    float bn = b[node];
    Hi[gid] = bn * mW1[129 * HMID + dm];
    Hj[gid] = bn * mW1[130 * HMID + dm] + mb1[dm];
}

// ---------------------------------------------------------------------------
// transpose W_ih / W_hh (192x64 -> 64x192) for coalesced GRU reads
// ---------------------------------------------------------------------------
__global__ void transpose_w_kernel(const float* __restrict__ W_ih,
                                   const float* __restrict__ W_hh,
                                   float* __restrict__ WT_ih,
                                   float* __restrict__ WT_hh) {
    int idx = blockIdx.x * 256 + threadIdx.x;
    if (idx < 192 * 64) {
        int g = idx / 64, k = idx % 64;
        WT_ih[k * 192 + g] = W_ih[idx];
        WT_hh[k * 192 + g] = W_hh[idx];
    }
}

// ---------------------------------------------------------------------------
// main: 64-pair tiles (4i x 16j), double-f16 3-term MFMA, 2-barrier pipeline:
//   P1: GEMM1(t) + epilogue->H2p + stage Hi/J(t+1)   | barrier
//   P2: GEMM2(t)  ||  pre(t+1)->H1                   | barrier
// H2p: (h,l)-packed u32, row-major [64][128], dword-swizzle col^((row&7)<<2).
// ---------------------------------------------------------------------------
__global__ __launch_bounds__(256, 2) void main_step_kernel(
    const float* __restrict__ Hi, const float* __restrict__ Hj,
    const float* __restrict__ J, const float* __restrict__ wJ_g,
    const float* __restrict__ mW2, const float* __restrict__ mb2,
    const float* __restrict__ mW3, float* __restrict__ msg) {

    __shared__ __align__(16) _Float16 H1h[64 * 128];      // 16 KB
    __shared__ __align__(16) _Float16 H1l[64 * 128];      // 16 KB
    __shared__ __align__(16) uint32_t H2p[64 * 128];      // 32 KB
    __shared__ __align__(16) float HiT[4 * 132];          // ~2.1 KB
    __shared__ float Jt[64];

    const int t   = threadIdx.x;
    const int w   = t >> 6;      // wave 0..3
    const int l   = t & 63;
    const int l16 = l & 15;
    const int lg  = l >> 4;      // 0..3

    const int j0 = (blockIdx.x & 31) * 16;
    const int ig = blockIdx.x >> 5;          // 0..15

    // ---- per-thread block-constant registers: Hj slice, wJ slice ----
    const int lj = t >> 4;       // 0..15  (pre-phase j index)
    const int c  = t & 15;       // 0..15  (pre-phase d-chunk)
    fvec4 hjv0 = *(const fvec4*)&Hj[(j0 + lj) * HMID + c * 8];
    fvec4 hjv1 = *(const fvec4*)&Hj[(j0 + lj) * HMID + c * 8 + 4];
    fvec4 wjv0 = *(const fvec4*)&wJ_g[c * 8];
    fvec4 wjv1 = *(const fvec4*)&wJ_g[c * 8 + 4];

    // ---- weight fragments (hi+lo f16) in registers ----
    half8 w2h[2][4], w2l[2][4], w3h[4], w3l[4];
    float mb2v[2];
    #pragma unroll
    for (int nb = 0; nb < 2; ++nb) {
        int col = w * 32 + nb * 16 + l16;
        mb2v[nb] = mb2[col];
        #pragma unroll
        for (int kb = 0; kb < 4; ++kb)
            #pragma unroll
            for (int i = 0; i < 8; ++i) {
                int k = kb * 32 + lg * 8 + i;
                float wv = mW2[k * HMID + col];
                _Float16 hh = (_Float16)wv;
                w2h[nb][kb][i] = hh;
                w2l[nb][kb][i] = (_Float16)(wv - (float)hh);
            }
    }
    {
        int col = w * 16 + l16;
        #pragma unroll
        for (int kb = 0; kb < 4; ++kb)
            #pragma unroll
            for (int i = 0; i < 8; ++i) {
                int k = kb * 32 + lg * 8 + i;
                float wv = mW3[k * MM + col];
                _Float16 hh = (_Float16)wv;
                w3h[kb][i] = hh;
                w3l[kb][i] = (_Float16)(wv - (float)hh);
            }
    }

    // ---- prologue: stage HiT/Jt for tile 0 ----
    if (t < 128) {
        int row = t >> 5, off = (t & 31) * 4;
        *(fvec4*)&HiT[row * 132 + off] =
            *(const fvec4*)&Hi[(ig * 32 + row) * HMID + off];
    }
    if (l < 16)
        Jt[w * 16 + l] = J[(ig * 32 + w) * NN + j0 + l];
    __syncthreads();

    // ---- pre: H1 = relu(Hi + Hj + J*wJ) -> f16 hi/lo (swizzled) ----
    auto do_pre = [&]() {
        #pragma unroll
        for (int it = 0; it < 4; ++it) {
            int p = it * 16 + lj;
            float Jw = Jt[p];
            fvec4 hi0 = *(const fvec4*)&HiT[it * 132 + c * 8];
            fvec4 hi1 = *(const fvec4*)&HiT[it * 132 + c * 8 + 4];
            half8 hvh, hvl;
            #pragma unroll
            for (int u = 0; u < 4; ++u) {
                float v0 = hi0[u] + hjv0[u] + Jw * wjv0[u];
                float v1 = hi1[u] + hjv1[u] + Jw * wjv1[u];
                v0 = v0 > 0.f ? v0 : 0.f;
                v1 = v1 > 0.f ? v1 : 0.f;
                _Float16 h0 = (_Float16)v0, h1 = (_Float16)v1;
                hvh[u]     = h0;
                hvh[u + 4] = h1;
                hvl[u]     = (_Float16)(v0 - (float)h0);
                hvl[u + 4] = (_Float16)(v1 - (float)h1);
            }
            int addr = p * 128 + ((c ^ lj) << 3);
            *(half8*)&H1h[addr] = hvh;
            *(half8*)&H1l[addr] = hvl;
        }
    };
    do_pre();
    __syncthreads();

    // persistent GEMM2 accumulators (summed over all i-tiles)
    f32x4 acc2[4];
    #pragma unroll
    for (int mb = 0; mb < 4; ++mb) acc2[mb] = (f32x4){0.f, 0.f, 0.f, 0.f};

    for (int tt = 0; tt < 8; ++tt) {
        // ================= P1: GEMM1(t) + epilogue + stage(t+1) ==========
        const int i0n = (ig * 8 + tt + 1) * 4;
        fvec4 hiStage;
        float jStage;
        const bool hasHi = (tt < 7) && (t < 128);
        const bool hasJ  = (tt < 7) && (l < 16);
        if (hasHi) {
            int row = t >> 5, off = (t & 31) * 4;
            hiStage = *(const fvec4*)&Hi[(i0n + row) * HMID + off];
        }
        if (hasJ) jStage = J[(i0n + w) * NN + j0 + l];

        {
            f32x4 acc[4][2];
            #pragma unroll
            for (int mb = 0; mb < 4; ++mb)
                #pragma unroll
                for (int nb = 0; nb < 2; ++nb)
                    acc[mb][nb] = (f32x4){0.f, 0.f, 0.f, 0.f};
            #pragma unroll
            for (int kb = 0; kb < 4; ++kb) {
                #pragma unroll
                for (int mb = 0; mb < 4; ++mb) {
                    int row = mb * 16 + l16;
                    int base = row * 128 + (((kb * 4 + lg) ^ l16) << 3);
                    half8 ah = *(const half8*)&H1h[base];
                    half8 al = *(const half8*)&H1l[base];
                    #pragma unroll
                    for (int nb = 0; nb < 2; ++nb) {
                        acc[mb][nb] = __builtin_amdgcn_mfma_f32_16x16x32_f16(
                            ah, w2h[nb][kb], acc[mb][nb], 0, 0, 0);
                        acc[mb][nb] = __builtin_amdgcn_mfma_f32_16x16x32_f16(
                            al, w2h[nb][kb], acc[mb][nb], 0, 0, 0);
                        acc[mb][nb] = __builtin_amdgcn_mfma_f32_16x16x32_f16(
                            ah, w2l[nb][kb], acc[mb][nb], 0, 0, 0);
                    }
                }
            }
            // epilogue: +bias, relu, split, pack (h,l)->u32, scatter b32
            // (row-major swizzled; banks 2-way across lanes -> free)
            #pragma unroll
            for (int mb = 0; mb < 4; ++mb)
                #pragma unroll
                for (int nbl = 0; nbl < 2; ++nbl) {
                    int col = w * 32 + nbl * 16 + l16;
                    #pragma unroll
                    for (int q = 0; q < 4; ++q) {
                        int row = mb * 16 + lg * 4 + q;
                        float v = acc[mb][nbl][q] + mb2v[nbl];
                        v = v > 0.f ? v : 0.f;
                        _Float16 hh = (_Float16)v;
                        _Float16 ll = (_Float16)(v - (float)hh);
                        uint16_t uh = __builtin_bit_cast(uint16_t, hh);
                        uint16_t ul = __builtin_bit_cast(uint16_t, ll);
                        H2p[row * 128 + (col ^ ((row & 7) << 2))] =
                            (uint32_t)uh | ((uint32_t)ul << 16);
                    }
                }
        }
        // publish stage(t+1)
        if (hasHi) {
            int row = t >> 5, off = (t & 31) * 4;
            *(fvec4*)&HiT[row * 132 + off] = hiStage;
        }
        if (hasJ) Jt[w * 16 + l] = jStage;
        __syncthreads();

        // ================= P2: GEMM2(t)  ||  pre(t+1) ====================
        #pragma unroll
        for (int kb = 0; kb < 4; ++kb) {
            #pragma unroll
            for (int mb2 = 0; mb2 < 4; ++mb2) {
                int row = mb2 * 16 + l16;
                int v = (row & 7) << 2;
                int cc = kb * 32 + lg * 8;
                const uint32_t* bp = &H2p[row * 128];
                u32x4 A = *(const u32x4*)&bp[cc ^ v];
                u32x4 B = *(const u32x4*)&bp[(cc + 4) ^ v];
                union { uint32_t wd[4]; half8 hv; } Ah, Al;
                Ah.wd[0] = __builtin_amdgcn_perm(A[1], A[0], 0x05040100u);
                Ah.wd[1] = __builtin_amdgcn_perm(A[3], A[2], 0x05040100u);
                Ah.wd[2] = __builtin_amdgcn_perm(B[1], B[0], 0x05040100u);
                Ah.wd[3] = __builtin_amdgcn_perm(B[3], B[2], 0x05040100u);
                Al.wd[0] = __builtin_amdgcn_perm(A[1], A[0], 0x07060302u);
                Al.wd[1] = __builtin_amdgcn_perm(A[3], A[2], 0x07060302u);
                Al.wd[2] = __builtin_amdgcn_perm(B[1], B[0], 0x07060302u);
                Al.wd[3] = __builtin_amdgcn_perm(B[3], B[2], 0x07060302u);
                acc2[mb2] = __builtin_amdgcn_mfma_f32_16x16x32_f16(
                    Ah.hv, w3h[kb], acc2[mb2], 0, 0, 0);
                acc2[mb2] = __builtin_amdgcn_mfma_f32_16x16x32_f16(
                    Al.hv, w3h[kb], acc2[mb2], 0, 0, 0);
                acc2[mb2] = __builtin_amdgcn_mfma_f32_16x16x32_f16(
                    Ah.hv, w3l[kb], acc2[mb2], 0, 0, 0);
            }
        }
        if (tt < 7) do_pre();
        __syncthreads();
    }

    // ---- final: reduce over mb2 (i-blocks) and atomically add to msg ----
    {
        int colm = w * 16 + l16;
        #pragma unroll
        for (int q = 0; q < 4; ++q) {
            float s = acc2[0][q] + acc2[1][q] + acc2[2][q] + acc2[3][q];
            atomicAdd(&msg[(j0 + lg * 4 + q) * MM + colm], s);
        }
    }
}

// ---------------------------------------------------------------------------
// GRU update + next-step Hi/Hj.  256 threads per node (4-way k-split gates,
// 2x128 Hi/Hj). Also zeroes msg for the next step's accumulation.
// ---------------------------------------------------------------------------
__global__ __launch_bounds__(256) void gru_kernel(
    float* __restrict__ msg, const float* __restrict__ mb3,
    const float* __restrict__ WT_ih, const float* __restrict__ b_ih,
    const float* __restrict__ WT_hh, const float* __restrict__ b_hh,
    float* __restrict__ h, const float* __restrict__ bvec,
    const float* __restrict__ mW1, const float* __restrict__ mb1,
    float* __restrict__ Hi, float* __restrict__ Hj, int lastStep) {

    __shared__ float xb[64], hb[64], hnb[64];
    __shared__ float red[4][6][64];
    int t = threadIdx.x;
    int d = t & 63;
    int p = t >> 6;              // 0..3
    int node = blockIdx.x;

    if (p == 0) {
        float x = msg[node * MM + d] + 512.0f * mb3[d];
        msg[node * MM + d] = 0.0f;          // pre-zero for next step
        xb[d] = x;
        hb[d] = h[node * SS + d];
    }
    __syncthreads();

    {
        float s0 = 0.f, s1 = 0.f, s2 = 0.f, s3 = 0.f, s4 = 0.f, s5 = 0.f;
        int k0 = p * 16;
        for (int kk = 0; kk < 16; ++kk) {
            int k = k0 + kk;
            float xk = xb[k], hk = hb[k];
            const float* wi = &WT_ih[k * 192];
            const float* wh = &WT_hh[k * 192];
            s0 += wi[d] * xk;
            s1 += wi[64 + d] * xk;
            s2 += wi[128 + d] * xk;
            s3 += wh[d] * hk;
            s4 += wh[64 + d] * hk;
            s5 += wh[128 + d] * hk;
        }
        red[p][0][d] = s0; red[p][1][d] = s1; red[p][2][d] = s2;
        red[p][3][d] = s3; red[p][4][d] = s4; red[p][5][d] = s5;
    }
    __syncthreads();

    if (p == 0) {
        float gxr = b_ih[d]       + red[0][0][d] + red[1][0][d] + red[2][0][d] + red[3][0][d];
        float gxz = b_ih[64 + d]  + red[0][1][d] + red[1][1][d] + red[2][1][d] + red[3][1][d];
        float gxn = b_ih[128 + d] + red[0][2][d] + red[1][2][d] + red[2][2][d] + red[3][2][d];
        float ghr = b_hh[d]       + red[0][3][d] + red[1][3][d] + red[2][3][d] + red[3][3][d];
        float ghz = b_hh[64 + d]  + red[0][4][d] + red[1][4][d] + red[2][4][d] + red[3][4][d];
        float ghn = b_hh[128 + d] + red[0][5][d] + red[1][5][d] + red[2][5][d] + red[3][5][d];
        float r = 1.f / (1.f + expf(-(gxr + ghr)));
        float z = 1.f / (1.f + expf(-(gxz + ghz)));
        float nc = tanhf(gxn + r * ghn);
        float hnew = (1.f - z) * nc + z * hb[d];
        h[node * SS + d] = hnew;
        hnb[d] = hnew;
    }
    __syncthreads();

    if (!lastStep) {
        int dm = t & 127;
        int half = t >> 7;       // 0: Hi, 1: Hj
        float bn = bvec[node];
        if (half == 0) {
            float ai = bn * mW1[129 * HMID + dm];
            for (int k = 0; k < 64; ++k)
                ai += hnb[k] * mW1[k * HMID + dm];
            Hi[node * HMID + dm] = ai;
        } else {
            float aj = bn * mW1[130 * HMID + dm] + mb1[dm];
            for (int k = 0; k < 64; ++k)
                aj += hnb[k] * mW1[(64 + k) * HMID + dm];
            Hj[node * HMID + dm] = aj;
        }
    }
}

// ---------------------------------------------------------------------------
// readout: relu(h@rW1+rb1) -> relu(@rW2+rb2) -> @rW3+rb3 -> softmax(2)
// ---------------------------------------------------------------------------
__global__ __launch_bounds__(64) void readout_kernel(
    const float* __restrict__ h, const float* __restrict__ rW1,
    const float* __restrict__ rb1, const float* __restrict__ rW2,
    const float* __restrict__ rb2, const float* __restrict__ rW3,
    const float* __restrict__ rb3, float* __restrict__ out) {

    __shared__ float hbuf[64], o1[128], o2[128];
    int d = threadIdx.x;
    int node = blockIdx.x;

    hbuf[d] = h[node * SS + d];
    __syncthreads();
    for (int dd = 0; dd < 2; ++dd) {
        int dm = d + dd * 64;
        float a = rb1[dm];
        for (int k = 0; k < 64; ++k) a += hbuf[k] * rW1[k * 128 + dm];
        o1[dm] = a > 0.f ? a : 0.f;
    }
    __syncthreads();
    for (int dd = 0; dd < 2; ++dd) {
        int dm = d + dd * 64;
        float a = rb2[dm];
        for (int k = 0; k < 128; ++k) a += o1[k] * rW2[k * 128 + dm];
        o2[dm] = a > 0.f ? a : 0.f;
    }
    __syncthreads();
    float p0 = 0.f, p1 = 0.f;
    for (int dd = 0; dd < 2; ++dd) {
        int k = d + dd * 64;
        p0 += o2[k] * rW3[k * 2 + 0];
        p1 += o2[k] * rW3[k * 2 + 1];
    }
    for (int off = 32; off; off >>= 1) {
        p0 += __shfl_xor(p0, off);
        p1 += __shfl_xor(p1, off);
    }
    if (d == 0) {
        p0 += rb3[0];
        p1 += rb3[1];
        float m = fmaxf(p0, p1);
        float e0 = expf(p0 - m), e1 = expf(p1 - m);
        float s = e0 + e1;
        out[node * 2 + 0] = e0 / s;
        out[node * 2 + 1] = e1 / s;
    }
}

// ---------------------------------------------------------------------------
extern "C" void kernel_launch(void* const* d_in, const int* in_sizes, int n_in,
                              void* d_out, int out_size, void* d_ws,
                              size_t ws_size, hipStream_t stream) {
    const float* J    = (const float*)d_in[0];
    const float* b    = (const float*)d_in[1];
    const float* mW1  = (const float*)d_in[2];
    const float* mb1  = (const float*)d_in[3];
    const float* mW2  = (const float*)d_in[4];
    const float* mb2  = (const float*)d_in[5];
    const float* mW3  = (const float*)d_in[6];
    const float* mb3  = (const float*)d_in[7];
    const float* W_ih = (const float*)d_in[8];
    const float* b_ih = (const float*)d_in[9];
    const float* W_hh = (const float*)d_in[10];
    const float* b_hh = (const float*)d_in[11];
    const float* rW1  = (const float*)d_in[12];
    const float* rb1  = (const float*)d_in[13];
    const float* rW2  = (const float*)d_in[14];
    const float* rb2  = (const float*)d_in[15];
    const float* rW3  = (const float*)d_in[16];
    const float* rb3  = (const float*)d_in[17];
    float* out = (float*)d_out;

    float* ws    = (float*)d_ws;
    float* hbuf  = ws;                    // 512*64
    float* msg   = ws + 32768;            // 512*64
    float* Hi    = ws + 65536;            // 512*128
    float* Hj    = ws + 131072;           // 512*128
    float* WT_ih = ws + 196608;           // 64*192
    float* WT_hh = ws + 208896;           // 64*192

    hipMemsetAsync(hbuf, 0, NN * SS * sizeof(float), stream);
    hipMemsetAsync(msg, 0, NN * MM * sizeof(float), stream);
    prep0_kernel<<<256, 256, 0, stream>>>(b, mW1, mb1, Hi, Hj);
    transpose_w_kernel<<<48, 256, 0, stream>>>(W_ih, W_hh, WT_ih, WT_hh);

    for (int s = 0; s < 5; ++s) {
        main_step_kernel<<<512, 256, 0, stream>>>(Hi, Hj, J, mW1 + 128 * HMID,
                                                  mW2, mb2, mW3, msg);
        gru_kernel<<<512, 256, 0, stream>>>(msg, mb3, WT_ih, b_ih, WT_hh, b_hh,
                                            hbuf, b, mW1, mb1, Hi, Hj, s == 4);
    }
    readout_kernel<<<512, 64, 0, stream>>>(hbuf, rW1, rb1, rW2, rb2, rW3, rb3,
                                           out);
}